// Round 1
// baseline (69.427 us; speedup 1.0000x reference)
//
#include <hip/hip_runtime.h>
#include <math.h>

#define NN 512
#define DD 512
#define HH 64
#define OUTC 32

// ws layout (floats):
//   P1T  [H][N]   @ 0       (32768)
//   P2B  [N][H]   @ 32768   (32768)
//   XWT  [OUT][N] @ 65536   (16384)
//   RDV  [N]      @ 81920   (512)     rdv[i] = 1/sqrt(rowsum(A)+1)

// K1: P1T = (F @ W1[:D])^T ; P2B = F @ W1[D:] + b1 ; XWT = (F @ gcn_w)^T
__global__ __launch_bounds__(256) void k1_proj(
    const float* __restrict__ features,
    const float* __restrict__ rel_w1,
    const float* __restrict__ rel_b1,
    const float* __restrict__ gcn_w,
    float* __restrict__ p1t,
    float* __restrict__ p2b,
    float* __restrict__ xwt)
{
    const int ROWS = 4;
    __shared__ float sF[ROWS * DD];           // 8 KB
    const int t  = threadIdx.x;
    const int i0 = blockIdx.x * ROWS;

    // stage 4 contiguous feature rows into LDS (coalesced float4)
    const float4* src = (const float4*)(features + (size_t)i0 * DD);
    float4* dst = (float4*)sF;
    for (int q = t; q < ROWS * DD / 4; q += 256) dst[q] = src[q];
    __syncthreads();

    if (t < 160) {
        const float* wcol;
        int stride;
        if (t < 64)       { wcol = rel_w1 + t;                 stride = HH;   }
        else if (t < 128) { wcol = rel_w1 + DD * HH + (t - 64); stride = HH;   }
        else              { wcol = gcn_w + (t - 128);           stride = OUTC; }

        float acc0 = 0.f, acc1 = 0.f, acc2 = 0.f, acc3 = 0.f;
        #pragma unroll 8
        for (int d = 0; d < DD; ++d) {
            float w = wcol[(size_t)d * stride];   // coalesced across lanes
            acc0 = fmaf(sF[0 * DD + d], w, acc0); // LDS broadcast
            acc1 = fmaf(sF[1 * DD + d], w, acc1);
            acc2 = fmaf(sF[2 * DD + d], w, acc2);
            acc3 = fmaf(sF[3 * DD + d], w, acc3);
        }

        if (t < 64) {
            float* p = p1t + (size_t)t * NN + i0;
            p[0] = acc0; p[1] = acc1; p[2] = acc2; p[3] = acc3;
        } else if (t < 128) {
            int h = t - 64;
            float b = rel_b1[h];
            p2b[(size_t)(i0 + 0) * HH + h] = acc0 + b;
            p2b[(size_t)(i0 + 1) * HH + h] = acc1 + b;
            p2b[(size_t)(i0 + 2) * HH + h] = acc2 + b;
            p2b[(size_t)(i0 + 3) * HH + h] = acc3 + b;
        } else {
            int c = t - 128;
            float* p = xwt + (size_t)c * NN + i0;
            p[0] = acc0; p[1] = acc1; p[2] = acc2; p[3] = acc3;
        }
    }
}

// K2: araw[i][j] = sigmoid(relu(P1[j]+P2b[i]) . w2 + b2) + (i==j)
//     rdv[i] = 1/sqrt(rowsum + 1)
__global__ __launch_bounds__(256) void k2_adj(
    const float* __restrict__ p1t,
    const float* __restrict__ p2b,
    const float* __restrict__ rel_w2,
    const float* __restrict__ rel_b2,
    float* __restrict__ araw,     // d_out A region (raw, normalized later)
    float* __restrict__ rdv)
{
    const int TI = 2;
    __shared__ float sp2[TI][HH];
    __shared__ float sw2[HH];
    __shared__ float sred[TI][4];
    const int t  = threadIdx.x;
    const int i0 = blockIdx.x * TI;

    if (t < HH) sw2[t] = rel_w2[t];
    else if (t < HH + TI * HH) {
        int q = t - HH;                      // 0..127 -> rows i0, i0+1
        sp2[q >> 6][q & 63] = p2b[(size_t)i0 * HH + q];
    }
    __syncthreads();

    const float b2 = rel_b2[0];
    float rs0 = 0.f, rs1 = 0.f;

    #pragma unroll
    for (int jj = 0; jj < 2; ++jj) {
        int j = t + jj * 256;
        float a0 = b2, a1 = b2;
        #pragma unroll 8
        for (int k = 0; k < HH; ++k) {
            float pv = p1t[(size_t)k * NN + j];   // coalesced across lanes
            float w  = sw2[k];                    // LDS broadcast
            a0 = fmaf(fmaxf(pv + sp2[0][k], 0.f), w, a0);
            a1 = fmaf(fmaxf(pv + sp2[1][k], 0.f), w, a1);
        }
        a0 = 1.f / (1.f + expf(-a0)); if (j == i0)     a0 += 1.f;
        a1 = 1.f / (1.f + expf(-a1)); if (j == i0 + 1) a1 += 1.f;
        araw[(size_t)(i0 + 0) * NN + j] = a0;
        araw[(size_t)(i0 + 1) * NN + j] = a1;
        rs0 += a0; rs1 += a1;
    }

    // 64-lane shuffle reduce, then cross-wave via LDS
    #pragma unroll
    for (int off = 32; off > 0; off >>= 1) {
        rs0 += __shfl_down(rs0, off, 64);
        rs1 += __shfl_down(rs1, off, 64);
    }
    int wave = t >> 6, lane = t & 63;
    if (lane == 0) { sred[0][wave] = rs0; sred[1][wave] = rs1; }
    __syncthreads();
    if (t < TI) {
        float s = sred[t][0] + sred[t][1] + sred[t][2] + sred[t][3];
        rdv[i0 + t] = 1.0f / sqrtf(s + 1.0f);
    }
}

// K3: normalize A in place; x = relu(gamma*(A@XW + b)*inv_sqrt(1+eps) + beta)
__global__ __launch_bounds__(256) void k3_gcn(
    const float* __restrict__ xwt,
    const float* __restrict__ rdv,
    const float* __restrict__ gcn_b,
    const float* __restrict__ bn_gamma,
    const float* __restrict__ bn_beta,
    float* __restrict__ outx,
    float* __restrict__ outA)
{
    __shared__ float sdv[NN];                 // 2 KB
    __shared__ float sred[4][OUTC];
    const int t = threadIdx.x;
    const int i = blockIdx.x;

    sdv[t] = rdv[t];
    sdv[t + 256] = rdv[t + 256];
    __syncthreads();

    const float ri = sdv[i];
    const int j0 = t, j1 = t + 256;
    float a0 = outA[(size_t)i * NN + j0] * (ri * sdv[j0]);
    float a1 = outA[(size_t)i * NN + j1] * (ri * sdv[j1]);
    outA[(size_t)i * NN + j0] = a0;
    outA[(size_t)i * NN + j1] = a1;

    float acc[OUTC];
    #pragma unroll
    for (int o = 0; o < OUTC; ++o) {
        acc[o] = fmaf(a0, xwt[(size_t)o * NN + j0],
                      a1 * xwt[(size_t)o * NN + j1]);   // coalesced loads
    }

    #pragma unroll
    for (int o = 0; o < OUTC; ++o)
        #pragma unroll
        for (int off = 32; off > 0; off >>= 1)
            acc[o] += __shfl_down(acc[o], off, 64);

    int wave = t >> 6, lane = t & 63;
    if (lane == 0) {
        #pragma unroll
        for (int o = 0; o < OUTC; ++o) sred[wave][o] = acc[o];
    }
    __syncthreads();
    if (t < OUTC) {
        float v = sred[0][t] + sred[1][t] + sred[2][t] + sred[3][t] + gcn_b[t];
        float invs = 1.0f / sqrtf(1.0f + 1e-5f);
        v = bn_gamma[t] * v * invs + bn_beta[t];
        outx[(size_t)i * OUTC + t] = fmaxf(v, 0.f);
    }
}

extern "C" void kernel_launch(void* const* d_in, const int* in_sizes, int n_in,
                              void* d_out, int out_size, void* d_ws, size_t ws_size,
                              hipStream_t stream) {
    const float* features = (const float*)d_in[0];
    const float* rel_w1   = (const float*)d_in[1];
    const float* rel_b1   = (const float*)d_in[2];
    const float* rel_w2   = (const float*)d_in[3];
    const float* rel_b2   = (const float*)d_in[4];
    const float* gcn_w    = (const float*)d_in[5];
    const float* gcn_b    = (const float*)d_in[6];
    const float* bn_gamma = (const float*)d_in[7];
    const float* bn_beta  = (const float*)d_in[8];

    float* out  = (float*)d_out;
    float* outx = out;                 // (512, 32)
    float* outA = out + NN * OUTC;     // (512, 512)

    float* ws  = (float*)d_ws;
    float* p1t = ws;                   // [64][512]
    float* p2b = ws + 32768;           // [512][64]
    float* xwt = ws + 65536;           // [32][512]
    float* rdv = ws + 81920;           // [512]

    hipLaunchKernelGGL(k1_proj, dim3(128), dim3(256), 0, stream,
                       features, rel_w1, rel_b1, gcn_w, p1t, p2b, xwt);
    hipLaunchKernelGGL(k2_adj, dim3(256), dim3(256), 0, stream,
                       p1t, p2b, rel_w2, rel_b2, outA, rdv);
    hipLaunchKernelGGL(k3_gcn, dim3(512), dim3(256), 0, stream,
                       xwt, rdv, gcn_b, bn_gamma, bn_beta, outx, outA);
}

// Round 2
// 45.492 us; speedup vs baseline: 1.5261x; 1.5261x over previous
//
#include <hip/hip_runtime.h>
#include <math.h>

#define NN 512
#define DD 512
#define HH 64
#define OUTC 32

// ws layout (floats):
//   P1T  [H][N]   @ 0       (32768)   P1T[h][i] = (F @ W1[:D])[i][h]
//   P2B  [N][H]   @ 32768   (32768)   P2B[i][h] = (F @ W1[D:])[i][h] + b1[h]
//   XWT  [OUT][N] @ 65536   (16384)   XWT[o][i] = (F @ gcn_w)[i][o]
//   RDV  [N]      @ 81920   (512)     rdv[i] = 1/sqrt(rowsum(A)+1)

// K1: C[512][160] = F[512][512] @ W[512][160], W = [W1a | W1b | gcn_w].
// No LDS: W via float4 (row-major contiguous), F via same-address L2 broadcast.
// grid 48 = 16 rowtiles (BM=32) x 3 coltiles; thread = 2 rows x 4 cols.
__global__ __launch_bounds__(256) void k1_gemm(
    const float* __restrict__ features,
    const float* __restrict__ rel_w1,
    const float* __restrict__ rel_b1,
    const float* __restrict__ gcn_w,
    float* __restrict__ p1t,
    float* __restrict__ p2b,
    float* __restrict__ xwt)
{
    const int t  = threadIdx.x;
    const int rt = blockIdx.x & 15;
    const int ct = blockIdx.x >> 4;

    const int m0 = rt * 32 + (t >> 4) * 2;
    int cloc = (t & 15) * 4;
    bool active = true;
    const float* wbase;
    int wstride;
    if (ct == 0)      { wbase = rel_w1;            wstride = HH; }
    else if (ct == 1) { wbase = rel_w1 + DD * HH;  wstride = HH; }
    else              { wbase = gcn_w;             wstride = OUTC;
                        if (cloc >= OUTC) { active = false; cloc = 0; } }

    const float* f0p = features + (size_t)m0 * DD;
    const float* f1p = f0p + DD;
    const float* wp  = wbase + cloc;

    float a00 = 0.f, a01 = 0.f, a02 = 0.f, a03 = 0.f;
    float a10 = 0.f, a11 = 0.f, a12 = 0.f, a13 = 0.f;

    #pragma unroll 8
    for (int k = 0; k < DD; ++k) {
        float4 w = *(const float4*)(wp + (size_t)k * wstride);
        float f0 = f0p[k];
        float f1 = f1p[k];
        a00 = fmaf(f0, w.x, a00); a01 = fmaf(f0, w.y, a01);
        a02 = fmaf(f0, w.z, a02); a03 = fmaf(f0, w.w, a03);
        a10 = fmaf(f1, w.x, a10); a11 = fmaf(f1, w.y, a11);
        a12 = fmaf(f1, w.z, a12); a13 = fmaf(f1, w.w, a13);
    }

    if (ct == 0) {
        // p1t[c][m]: store {row m0, row m0+1} as float2 per col
        float2 v;
        v.x = a00; v.y = a10; *(float2*)(p1t + (size_t)(cloc + 0) * NN + m0) = v;
        v.x = a01; v.y = a11; *(float2*)(p1t + (size_t)(cloc + 1) * NN + m0) = v;
        v.x = a02; v.y = a12; *(float2*)(p1t + (size_t)(cloc + 2) * NN + m0) = v;
        v.x = a03; v.y = a13; *(float2*)(p1t + (size_t)(cloc + 3) * NN + m0) = v;
    } else if (ct == 1) {
        // p2b[m][h] += b1, contiguous float4 over h
        float4 b = *(const float4*)(rel_b1 + cloc);
        float4 r0 = make_float4(a00 + b.x, a01 + b.y, a02 + b.z, a03 + b.w);
        float4 r1 = make_float4(a10 + b.x, a11 + b.y, a12 + b.z, a13 + b.w);
        *(float4*)(p2b + (size_t)(m0 + 0) * HH + cloc) = r0;
        *(float4*)(p2b + (size_t)(m0 + 1) * HH + cloc) = r1;
    } else if (active) {
        // xwt[o][m]: float2 per col
        float2 v;
        v.x = a00; v.y = a10; *(float2*)(xwt + (size_t)(cloc + 0) * NN + m0) = v;
        v.x = a01; v.y = a11; *(float2*)(xwt + (size_t)(cloc + 1) * NN + m0) = v;
        v.x = a02; v.y = a12; *(float2*)(xwt + (size_t)(cloc + 2) * NN + m0) = v;
        v.x = a03; v.y = a13; *(float2*)(xwt + (size_t)(cloc + 3) * NN + m0) = v;
    }
}

// K2: araw[i][j] = sigmoid(relu(P1[j]+P2b[i]) . w2 + b2) + (i==j)
//     rdv[i] = 1/sqrt(rowsum + 1)
__global__ __launch_bounds__(256) void k2_adj(
    const float* __restrict__ p1t,
    const float* __restrict__ p2b,
    const float* __restrict__ rel_w2,
    const float* __restrict__ rel_b2,
    float* __restrict__ araw,     // d_out A region (raw, normalized later)
    float* __restrict__ rdv)
{
    const int TI = 2;
    __shared__ float sp2[TI][HH];
    __shared__ float sw2[HH];
    __shared__ float sred[TI][4];
    const int t  = threadIdx.x;
    const int i0 = blockIdx.x * TI;

    if (t < HH) sw2[t] = rel_w2[t];
    else if (t < HH + TI * HH) {
        int q = t - HH;                      // 0..127 -> rows i0, i0+1
        sp2[q >> 6][q & 63] = p2b[(size_t)i0 * HH + q];
    }
    __syncthreads();

    const float b2 = rel_b2[0];
    float rs0 = 0.f, rs1 = 0.f;

    #pragma unroll
    for (int jj = 0; jj < 2; ++jj) {
        int j = t + jj * 256;
        float a0 = b2, a1 = b2;
        #pragma unroll 8
        for (int k = 0; k < HH; ++k) {
            float pv = p1t[(size_t)k * NN + j];   // coalesced across lanes
            float w  = sw2[k];                    // LDS broadcast
            a0 = fmaf(fmaxf(pv + sp2[0][k], 0.f), w, a0);
            a1 = fmaf(fmaxf(pv + sp2[1][k], 0.f), w, a1);
        }
        a0 = 1.f / (1.f + expf(-a0)); if (j == i0)     a0 += 1.f;
        a1 = 1.f / (1.f + expf(-a1)); if (j == i0 + 1) a1 += 1.f;
        araw[(size_t)(i0 + 0) * NN + j] = a0;
        araw[(size_t)(i0 + 1) * NN + j] = a1;
        rs0 += a0; rs1 += a1;
    }

    // 64-lane shuffle reduce, then cross-wave via LDS
    #pragma unroll
    for (int off = 32; off > 0; off >>= 1) {
        rs0 += __shfl_down(rs0, off, 64);
        rs1 += __shfl_down(rs1, off, 64);
    }
    int wave = t >> 6, lane = t & 63;
    if (lane == 0) { sred[0][wave] = rs0; sred[1][wave] = rs1; }
    __syncthreads();
    if (t < TI) {
        float s = sred[t][0] + sred[t][1] + sred[t][2] + sred[t][3];
        rdv[i0 + t] = 1.0f / sqrtf(s + 1.0f);
    }
}

// K3: normalize A in place; x = relu(gamma*(A@XW + b)*inv_sqrt(1+eps) + beta)
__global__ __launch_bounds__(256) void k3_gcn(
    const float* __restrict__ xwt,
    const float* __restrict__ rdv,
    const float* __restrict__ gcn_b,
    const float* __restrict__ bn_gamma,
    const float* __restrict__ bn_beta,
    float* __restrict__ outx,
    float* __restrict__ outA)
{
    __shared__ float sdv[NN];                 // 2 KB
    __shared__ float sred[4][OUTC];
    const int t = threadIdx.x;
    const int i = blockIdx.x;

    sdv[t] = rdv[t];
    sdv[t + 256] = rdv[t + 256];
    __syncthreads();

    const float ri = sdv[i];
    const int j0 = t, j1 = t + 256;
    float a0 = outA[(size_t)i * NN + j0] * (ri * sdv[j0]);
    float a1 = outA[(size_t)i * NN + j1] * (ri * sdv[j1]);
    outA[(size_t)i * NN + j0] = a0;
    outA[(size_t)i * NN + j1] = a1;

    float acc[OUTC];
    #pragma unroll
    for (int o = 0; o < OUTC; ++o) {
        acc[o] = fmaf(a0, xwt[(size_t)o * NN + j0],
                      a1 * xwt[(size_t)o * NN + j1]);   // coalesced loads
    }

    #pragma unroll
    for (int o = 0; o < OUTC; ++o)
        #pragma unroll
        for (int off = 32; off > 0; off >>= 1)
            acc[o] += __shfl_down(acc[o], off, 64);

    int wave = t >> 6, lane = t & 63;
    if (lane == 0) {
        #pragma unroll
        for (int o = 0; o < OUTC; ++o) sred[wave][o] = acc[o];
    }
    __syncthreads();
    if (t < OUTC) {
        float v = sred[0][t] + sred[1][t] + sred[2][t] + sred[3][t] + gcn_b[t];
        float invs = 1.0f / sqrtf(1.0f + 1e-5f);
        v = bn_gamma[t] * v * invs + bn_beta[t];
        outx[(size_t)i * OUTC + t] = fmaxf(v, 0.f);
    }
}

extern "C" void kernel_launch(void* const* d_in, const int* in_sizes, int n_in,
                              void* d_out, int out_size, void* d_ws, size_t ws_size,
                              hipStream_t stream) {
    const float* features = (const float*)d_in[0];
    const float* rel_w1   = (const float*)d_in[1];
    const float* rel_b1   = (const float*)d_in[2];
    const float* rel_w2   = (const float*)d_in[3];
    const float* rel_b2   = (const float*)d_in[4];
    const float* gcn_w    = (const float*)d_in[5];
    const float* gcn_b    = (const float*)d_in[6];
    const float* bn_gamma = (const float*)d_in[7];
    const float* bn_beta  = (const float*)d_in[8];

    float* out  = (float*)d_out;
    float* outx = out;                 // (512, 32)
    float* outA = out + NN * OUTC;     // (512, 512)

    float* ws  = (float*)d_ws;
    float* p1t = ws;                   // [64][512]
    float* p2b = ws + 32768;           // [512][64]
    float* xwt = ws + 65536;           // [32][512]
    float* rdv = ws + 81920;           // [512]

    hipLaunchKernelGGL(k1_gemm, dim3(48), dim3(256), 0, stream,
                       features, rel_w1, rel_b1, gcn_w, p1t, p2b, xwt);
    hipLaunchKernelGGL(k2_adj, dim3(256), dim3(256), 0, stream,
                       p1t, p2b, rel_w2, rel_b2, outA, rdv);
    hipLaunchKernelGGL(k3_gcn, dim3(512), dim3(256), 0, stream,
                       xwt, rdv, gcn_b, bn_gamma, bn_beta, outx, outA);
}

// Round 3
// 40.064 us; speedup vs baseline: 1.7329x; 1.1355x over previous
//
#include <hip/hip_runtime.h>
#include <math.h>

#define NN 512
#define DD 512
#define HH 64
#define OUTC 32

// ws layout (floats):
//   P1T  [H][N]   @ 0       (32768)   P1T[h][i] = (F @ W1[:D])[i][h]
//   P2B  [N][H]   @ 32768   (32768)   P2B[i][h] = (F @ W1[D:])[i][h] + b1[h]
//   XWT  [OUT][N] @ 65536   (16384)   XWT[o][i] = (F @ gcn_w)[i][o]
//   RDV  [N]      @ 81920   (512)     rdv[i] = 1/sqrt(rowsum(A)+1)

// K1: C[512][160] = F[512][512] @ W[512][160], W = [W1a | W1b | gcn_w].
// 160 blocks = 32 row-tiles (16 rows) x 5 col-tiles (32 cols).
// Thread = 1 row x 2 adjacent cols. Explicit A/B group prefetch (8 k per
// group) so ~24 loads stay in flight; compiler refused to do this itself
// (VGPR=20/32, 230 cyc/k serial in rounds 1-2).
__global__ __launch_bounds__(256) void k1_gemm(
    const float* __restrict__ features,
    const float* __restrict__ rel_w1,
    const float* __restrict__ rel_b1,
    const float* __restrict__ gcn_w,
    float* __restrict__ p1t,
    float* __restrict__ p2b,
    float* __restrict__ xwt)
{
    const int t  = threadIdx.x;
    const int bi = blockIdx.x & 31;        // row block (16 rows)
    const int bc = blockIdx.x >> 5;        // col block 0..4 (32 cols)
    const int r  = t >> 4;                 // 0..15
    const int cp = (t & 15) * 2;           // 0,2,..,30 within col tile
    const int i  = bi * 16 + r;

    const float* wbase;
    int wstride;
    if (bc < 2)      { wbase = rel_w1 + bc * 32;                   wstride = HH;   }
    else if (bc < 4) { wbase = rel_w1 + DD * HH + (bc - 2) * 32;   wstride = HH;   }
    else             { wbase = gcn_w;                              wstride = OUTC; }

    const float* fp = features + (size_t)i * DD;
    const float* wp = wbase + cp;

    float accx = 0.f, accy = 0.f;

    float2 wA[8], wB[8];
    float4 fA0, fA1, fB0, fB1;

#define LOADG(k0, W, F0, F1)                                                   \
    {                                                                          \
        _Pragma("unroll")                                                      \
        for (int j = 0; j < 8; ++j)                                            \
            W[j] = *(const float2*)(wp + (size_t)((k0) + j) * wstride);        \
        F0 = *(const float4*)(fp + (k0));                                      \
        F1 = *(const float4*)(fp + (k0) + 4);                                  \
    }

#define COMPG(W, F0, F1)                                                       \
    {                                                                          \
        float fs[8] = {F0.x, F0.y, F0.z, F0.w, F1.x, F1.y, F1.z, F1.w};        \
        _Pragma("unroll")                                                      \
        for (int j = 0; j < 8; ++j) {                                          \
            accx = fmaf(fs[j], W[j].x, accx);                                  \
            accy = fmaf(fs[j], W[j].y, accy);                                  \
        }                                                                      \
    }

    LOADG(0, wA, fA0, fA1);
    #pragma unroll 1
    for (int g = 0; g < 64; g += 2) {
        LOADG((g + 1) * 8, wB, fB0, fB1);          // prefetch odd group
        COMPG(wA, fA0, fA1);
        if (g + 2 < 64) LOADG((g + 2) * 8, wA, fA0, fA1);  // prefetch even
        COMPG(wB, fB0, fB1);
    }
#undef LOADG
#undef COMPG

    if (bc < 2) {
        int c0 = bc * 32 + cp;
        p1t[(size_t)(c0 + 0) * NN + i] = accx;
        p1t[(size_t)(c0 + 1) * NN + i] = accy;
    } else if (bc < 4) {
        int h = (bc - 2) * 32 + cp;
        float2 b = *(const float2*)(rel_b1 + h);
        float2 v = make_float2(accx + b.x, accy + b.y);
        *(float2*)(p2b + (size_t)i * HH + h) = v;
    } else {
        int o = cp;
        xwt[(size_t)(o + 0) * NN + i] = accx;
        xwt[(size_t)(o + 1) * NN + i] = accy;
    }
}

// K2: araw[i][j] = sigmoid(relu(P1[j]+P2b[i]) . w2 + b2) + (i==j)
//     rdv[i] = 1/sqrt(rowsum + 1)
__global__ __launch_bounds__(256) void k2_adj(
    const float* __restrict__ p1t,
    const float* __restrict__ p2b,
    const float* __restrict__ rel_w2,
    const float* __restrict__ rel_b2,
    float* __restrict__ araw,     // d_out A region (raw, normalized later)
    float* __restrict__ rdv)
{
    const int TI = 2;
    __shared__ float sp2[TI][HH];
    __shared__ float sw2[HH];
    __shared__ float sred[TI][4];
    const int t  = threadIdx.x;
    const int i0 = blockIdx.x * TI;

    if (t < HH) sw2[t] = rel_w2[t];
    else if (t < HH + TI * HH) {
        int q = t - HH;                      // 0..127 -> rows i0, i0+1
        sp2[q >> 6][q & 63] = p2b[(size_t)i0 * HH + q];
    }
    __syncthreads();

    const float b2 = rel_b2[0];
    float rs0 = 0.f, rs1 = 0.f;

    #pragma unroll
    for (int jj = 0; jj < 2; ++jj) {
        int j = t + jj * 256;
        float a0 = b2, a1 = b2;
        #pragma unroll 8
        for (int k = 0; k < HH; ++k) {
            float pv = p1t[(size_t)k * NN + j];   // coalesced across lanes
            float w  = sw2[k];                    // LDS broadcast
            a0 = fmaf(fmaxf(pv + sp2[0][k], 0.f), w, a0);
            a1 = fmaf(fmaxf(pv + sp2[1][k], 0.f), w, a1);
        }
        a0 = 1.f / (1.f + expf(-a0)); if (j == i0)     a0 += 1.f;
        a1 = 1.f / (1.f + expf(-a1)); if (j == i0 + 1) a1 += 1.f;
        araw[(size_t)(i0 + 0) * NN + j] = a0;
        araw[(size_t)(i0 + 1) * NN + j] = a1;
        rs0 += a0; rs1 += a1;
    }

    // 64-lane shuffle reduce, then cross-wave via LDS
    #pragma unroll
    for (int off = 32; off > 0; off >>= 1) {
        rs0 += __shfl_down(rs0, off, 64);
        rs1 += __shfl_down(rs1, off, 64);
    }
    int wave = t >> 6, lane = t & 63;
    if (lane == 0) { sred[0][wave] = rs0; sred[1][wave] = rs1; }
    __syncthreads();
    if (t < TI) {
        float s = sred[t][0] + sred[t][1] + sred[t][2] + sred[t][3];
        rdv[i0 + t] = 1.0f / sqrtf(s + 1.0f);
    }
}

// K3: normalize A in place; x = relu(gamma*(A@XW + b)*inv_sqrt(1+eps) + beta)
__global__ __launch_bounds__(256) void k3_gcn(
    const float* __restrict__ xwt,
    const float* __restrict__ rdv,
    const float* __restrict__ gcn_b,
    const float* __restrict__ bn_gamma,
    const float* __restrict__ bn_beta,
    float* __restrict__ outx,
    float* __restrict__ outA)
{
    __shared__ float sdv[NN];                 // 2 KB
    __shared__ float sred[4][OUTC];
    const int t = threadIdx.x;
    const int i = blockIdx.x;

    sdv[t] = rdv[t];
    sdv[t + 256] = rdv[t + 256];
    __syncthreads();

    const float ri = sdv[i];
    const int j0 = t, j1 = t + 256;
    float a0 = outA[(size_t)i * NN + j0] * (ri * sdv[j0]);
    float a1 = outA[(size_t)i * NN + j1] * (ri * sdv[j1]);
    outA[(size_t)i * NN + j0] = a0;
    outA[(size_t)i * NN + j1] = a1;

    float acc[OUTC];
    #pragma unroll
    for (int o = 0; o < OUTC; ++o) {
        acc[o] = fmaf(a0, xwt[(size_t)o * NN + j0],
                      a1 * xwt[(size_t)o * NN + j1]);   // coalesced loads
    }

    #pragma unroll
    for (int o = 0; o < OUTC; ++o)
        #pragma unroll
        for (int off = 32; off > 0; off >>= 1)
            acc[o] += __shfl_down(acc[o], off, 64);

    int wave = t >> 6, lane = t & 63;
    if (lane == 0) {
        #pragma unroll
        for (int o = 0; o < OUTC; ++o) sred[wave][o] = acc[o];
    }
    __syncthreads();
    if (t < OUTC) {
        float v = sred[0][t] + sred[1][t] + sred[2][t] + sred[3][t] + gcn_b[t];
        float invs = 1.0f / sqrtf(1.0f + 1e-5f);
        v = bn_gamma[t] * v * invs + bn_beta[t];
        outx[(size_t)i * OUTC + t] = fmaxf(v, 0.f);
    }
}

extern "C" void kernel_launch(void* const* d_in, const int* in_sizes, int n_in,
                              void* d_out, int out_size, void* d_ws, size_t ws_size,
                              hipStream_t stream) {
    const float* features = (const float*)d_in[0];
    const float* rel_w1   = (const float*)d_in[1];
    const float* rel_b1   = (const float*)d_in[2];
    const float* rel_w2   = (const float*)d_in[3];
    const float* rel_b2   = (const float*)d_in[4];
    const float* gcn_w    = (const float*)d_in[5];
    const float* gcn_b    = (const float*)d_in[6];
    const float* bn_gamma = (const float*)d_in[7];
    const float* bn_beta  = (const float*)d_in[8];

    float* out  = (float*)d_out;
    float* outx = out;                 // (512, 32)
    float* outA = out + NN * OUTC;     // (512, 512)

    float* ws  = (float*)d_ws;
    float* p1t = ws;                   // [64][512]
    float* p2b = ws + 32768;           // [512][64]
    float* xwt = ws + 65536;           // [32][512]
    float* rdv = ws + 81920;           // [512]

    hipLaunchKernelGGL(k1_gemm, dim3(160), dim3(256), 0, stream,
                       features, rel_w1, rel_b1, gcn_w, p1t, p2b, xwt);
    hipLaunchKernelGGL(k2_adj, dim3(256), dim3(256), 0, stream,
                       p1t, p2b, rel_w2, rel_b2, outA, rdv);
    hipLaunchKernelGGL(k3_gcn, dim3(512), dim3(256), 0, stream,
                       xwt, rdv, gcn_b, bn_gamma, bn_beta, outx, outA);
}

// Round 4
// 37.608 us; speedup vs baseline: 1.8461x; 1.0653x over previous
//
#include <hip/hip_runtime.h>
#include <math.h>

#define NN 512
#define DD 512
#define HH 64
#define OUTC 32

// ws layout (floats):
//   P1T  [H][N]   @ 0       (32768)   P1T[h][i] = (F @ W1[:D])[i][h]
//   P2B  [N][H]   @ 32768   (32768)   P2B[i][h] = (F @ W1[D:])[i][h] + b1[h]
//   XWT  [OUT][N] @ 65536   (16384)   XWT[o][i] = (F @ gcn_w)[i][o]
//   RDV  [N]      @ 81920   (512)     rdv[i] = 1/sqrt(rowsum(A)+1)

// 512-deep dot with COMPILE-TIME column stride. Rounds 1-3 used a runtime
// stride -> per-load address chains -> compiler serialized every load
// (VGPR=20/32, ~230cyc/k). With STRIDE a template constant the 16 loads of a
// group share one base register + immediate offsets (<=15*STRIDE*4 < 4KiB),
// and the A/B prefetch keeps ~20 loads in flight.
template<int STRIDE>
__device__ __forceinline__ float dot512(const float* __restrict__ fp,
                                        const float* __restrict__ wp)
{
    float acc = 0.f;
    float wA[16], wB[16];
    float4 fA[4], fB[4];

#define LOADG(k0, W, F)                                                        \
    {                                                                          \
        _Pragma("unroll")                                                      \
        for (int j = 0; j < 16; ++j) W[j] = wp[(size_t)((k0) + j) * STRIDE];   \
        _Pragma("unroll")                                                      \
        for (int j = 0; j < 4; ++j)  F[j] = *(const float4*)(fp + (k0) + 4*j); \
    }
#define COMPG(W, F)                                                            \
    {                                                                          \
        float fs[16] = {F[0].x,F[0].y,F[0].z,F[0].w, F[1].x,F[1].y,F[1].z,F[1].w, \
                        F[2].x,F[2].y,F[2].z,F[2].w, F[3].x,F[3].y,F[3].z,F[3].w};\
        _Pragma("unroll")                                                      \
        for (int j = 0; j < 16; ++j) acc = fmaf(fs[j], W[j], acc);             \
    }

    LOADG(0, wA, fA);
    #pragma unroll 1
    for (int g = 0; g < 32; g += 2) {
        LOADG((g + 1) * 16, wB, fB);            // prefetch odd group
        COMPG(wA, fA);
        if (g + 2 < 32) LOADG((g + 2) * 16, wA, fA);   // prefetch even group
        COMPG(wB, fB);
    }
#undef LOADG
#undef COMPG
    return acc;
}

// K1: C[512][160] = F @ [W1a | W1b | gcn_w].
// blocks 0..255: P-part. thread -> (i = b*2 + t/128, c = t&127), stride 64.
//   c-major lanes => W reads are 256B contiguous per wave; F is lane-uniform.
// blocks 256..319: XW-part. thread -> (i = g/32, c = g&31), stride 32.
__global__ __launch_bounds__(256) void k1_gemm(
    const float* __restrict__ features,
    const float* __restrict__ rel_w1,
    const float* __restrict__ rel_b1,
    const float* __restrict__ gcn_w,
    float* __restrict__ p1t,
    float* __restrict__ p2b,
    float* __restrict__ xwt)
{
    const int t = threadIdx.x;
    const int b = blockIdx.x;
    if (b < 256) {
        const int i = b * 2 + (t >> 7);
        const int c = t & 127;
        const float* fp = features + (size_t)i * DD;
        const float* wp = rel_w1 + (c & 63) + (size_t)(c >> 6) * (DD * HH);
        float acc = dot512<HH>(fp, wp);
        if (c < 64) p1t[(size_t)c * NN + i] = acc;
        else        p2b[(size_t)i * HH + (c - 64)] = acc + rel_b1[c - 64];
    } else {
        const int g = (b - 256) * 256 + t;
        const int i = g >> 5;
        const int c = g & 31;
        float acc = dot512<OUTC>(features + (size_t)i * DD, gcn_w + c);
        xwt[(size_t)c * NN + i] = acc;
    }
}

// K2: araw[i][j] = sigmoid(relu(P1[j]+P2b[i]) . w2 + b2) + (i==j)
//     rdv[i] = 1/sqrt(rowsum + 1)
__global__ __launch_bounds__(256) void k2_adj(
    const float* __restrict__ p1t,
    const float* __restrict__ p2b,
    const float* __restrict__ rel_w2,
    const float* __restrict__ rel_b2,
    float* __restrict__ araw,     // d_out A region (raw, normalized later)
    float* __restrict__ rdv)
{
    const int TI = 2;
    __shared__ float sp2[TI][HH];
    __shared__ float sw2[HH];
    __shared__ float sred[TI][4];
    const int t  = threadIdx.x;
    const int i0 = blockIdx.x * TI;

    if (t < HH) sw2[t] = rel_w2[t];
    else if (t < HH + TI * HH) {
        int q = t - HH;                      // 0..127 -> rows i0, i0+1
        sp2[q >> 6][q & 63] = p2b[(size_t)i0 * HH + q];
    }
    __syncthreads();

    const float b2 = rel_b2[0];
    float rs0 = 0.f, rs1 = 0.f;

    #pragma unroll
    for (int jj = 0; jj < 2; ++jj) {
        int j = t + jj * 256;
        float a0 = b2, a1 = b2;
        #pragma unroll 8
        for (int k = 0; k < HH; ++k) {
            float pv = p1t[(size_t)k * NN + j];   // coalesced across lanes
            float w  = sw2[k];                    // LDS broadcast
            a0 = fmaf(fmaxf(pv + sp2[0][k], 0.f), w, a0);
            a1 = fmaf(fmaxf(pv + sp2[1][k], 0.f), w, a1);
        }
        a0 = 1.f / (1.f + expf(-a0)); if (j == i0)     a0 += 1.f;
        a1 = 1.f / (1.f + expf(-a1)); if (j == i0 + 1) a1 += 1.f;
        araw[(size_t)(i0 + 0) * NN + j] = a0;
        araw[(size_t)(i0 + 1) * NN + j] = a1;
        rs0 += a0; rs1 += a1;
    }

    // 64-lane shuffle reduce, then cross-wave via LDS
    #pragma unroll
    for (int off = 32; off > 0; off >>= 1) {
        rs0 += __shfl_down(rs0, off, 64);
        rs1 += __shfl_down(rs1, off, 64);
    }
    int wave = t >> 6, lane = t & 63;
    if (lane == 0) { sred[0][wave] = rs0; sred[1][wave] = rs1; }
    __syncthreads();
    if (t < TI) {
        float s = sred[t][0] + sred[t][1] + sred[t][2] + sred[t][3];
        rdv[i0 + t] = 1.0f / sqrtf(s + 1.0f);
    }
}

// K3: normalize A in place; x = relu(gamma*(A@XW + b)*inv_sqrt(1+eps) + beta)
__global__ __launch_bounds__(256) void k3_gcn(
    const float* __restrict__ xwt,
    const float* __restrict__ rdv,
    const float* __restrict__ gcn_b,
    const float* __restrict__ bn_gamma,
    const float* __restrict__ bn_beta,
    float* __restrict__ outx,
    float* __restrict__ outA)
{
    __shared__ float sdv[NN];                 // 2 KB
    __shared__ float sred[4][OUTC];
    const int t = threadIdx.x;
    const int i = blockIdx.x;

    sdv[t] = rdv[t];
    sdv[t + 256] = rdv[t + 256];
    __syncthreads();

    const float ri = sdv[i];
    const int j0 = t, j1 = t + 256;
    float a0 = outA[(size_t)i * NN + j0] * (ri * sdv[j0]);
    float a1 = outA[(size_t)i * NN + j1] * (ri * sdv[j1]);
    outA[(size_t)i * NN + j0] = a0;
    outA[(size_t)i * NN + j1] = a1;

    float acc[OUTC];
    #pragma unroll
    for (int o = 0; o < OUTC; ++o) {
        acc[o] = fmaf(a0, xwt[(size_t)o * NN + j0],
                      a1 * xwt[(size_t)o * NN + j1]);   // coalesced loads
    }

    #pragma unroll
    for (int o = 0; o < OUTC; ++o)
        #pragma unroll
        for (int off = 32; off > 0; off >>= 1)
            acc[o] += __shfl_down(acc[o], off, 64);

    int wave = t >> 6, lane = t & 63;
    if (lane == 0) {
        #pragma unroll
        for (int o = 0; o < OUTC; ++o) sred[wave][o] = acc[o];
    }
    __syncthreads();
    if (t < OUTC) {
        float v = sred[0][t] + sred[1][t] + sred[2][t] + sred[3][t] + gcn_b[t];
        float invs = 1.0f / sqrtf(1.0f + 1e-5f);
        v = bn_gamma[t] * v * invs + bn_beta[t];
        outx[(size_t)i * OUTC + t] = fmaxf(v, 0.f);
    }
}

extern "C" void kernel_launch(void* const* d_in, const int* in_sizes, int n_in,
                              void* d_out, int out_size, void* d_ws, size_t ws_size,
                              hipStream_t stream) {
    const float* features = (const float*)d_in[0];
    const float* rel_w1   = (const float*)d_in[1];
    const float* rel_b1   = (const float*)d_in[2];
    const float* rel_w2   = (const float*)d_in[3];
    const float* rel_b2   = (const float*)d_in[4];
    const float* gcn_w    = (const float*)d_in[5];
    const float* gcn_b    = (const float*)d_in[6];
    const float* bn_gamma = (const float*)d_in[7];
    const float* bn_beta  = (const float*)d_in[8];

    float* out  = (float*)d_out;
    float* outx = out;                 // (512, 32)
    float* outA = out + NN * OUTC;     // (512, 512)

    float* ws  = (float*)d_ws;
    float* p1t = ws;                   // [64][512]
    float* p2b = ws + 32768;           // [512][64]
    float* xwt = ws + 65536;           // [32][512]
    float* rdv = ws + 81920;           // [512]

    hipLaunchKernelGGL(k1_gemm, dim3(320), dim3(256), 0, stream,
                       features, rel_w1, rel_b1, gcn_w, p1t, p2b, xwt);
    hipLaunchKernelGGL(k2_adj, dim3(256), dim3(256), 0, stream,
                       p1t, p2b, rel_w2, rel_b2, outA, rdv);
    hipLaunchKernelGGL(k3_gcn, dim3(512), dim3(256), 0, stream,
                       xwt, rdv, gcn_b, bn_gamma, bn_beta, outx, outA);
}

// Round 5
// 32.736 us; speedup vs baseline: 2.1208x; 1.1488x over previous
//
#include <hip/hip_runtime.h>
#include <math.h>

#define NN 512
#define DD 512
#define HH 64
#define OUTC 32

// ws layout (floats):
//   P1T  [H][N]   @ 0       (32768)   P1T[h][i] = (F @ W1[:D])[i][h]
//   P2B  [N][H]   @ 32768   (32768)   P2B[i][h] = (F @ W1[D:])[i][h] + b1[h]
//   XWT  [OUT][N] @ 65536   (16384)   XWT[o][i] = (F @ gcn_w)[i][o]
//   RDV  [N]      @ 81920   (512)     rdv[i] = 1/sqrt(rowsum(A)+1)

// 64-term partial dot, compile-time W stride. Rounds 2-4 showed the compiler
// serializes these loads (1 outstanding/wave, ~130cyc each) no matter how the
// source is pipelined -> the fix is wave count, not ILP: split K 8-ways so
// occupancy saturates (40 waves/CU requested, 32 resident).
template<int STRIDE>
__device__ __forceinline__ float dot64(const float* __restrict__ fp,
                                       const float* __restrict__ wp)
{
    float acc = 0.f;
    #pragma unroll
    for (int q = 0; q < 16; ++q) {
        float4 f = *(const float4*)(fp + 4 * q);
        acc = fmaf(f.x, wp[(size_t)(4 * q + 0) * STRIDE], acc);
        acc = fmaf(f.y, wp[(size_t)(4 * q + 1) * STRIDE], acc);
        acc = fmaf(f.z, wp[(size_t)(4 * q + 2) * STRIDE], acc);
        acc = fmaf(f.w, wp[(size_t)(4 * q + 3) * STRIDE], acc);
    }
    return acc;
}

// K1: C[512][160] = F @ [W1a | W1b | gcn_w], split-K 8.
// grid (cg=0..4, i=0..511); thread: tc = t&31 (col within group), kc = t>>5.
// Each thread: 64-term partial; LDS [kc][tc] reduce; first 32 threads emit.
__global__ __launch_bounds__(256) void k1_gemm(
    const float* __restrict__ features,
    const float* __restrict__ rel_w1,
    const float* __restrict__ rel_b1,
    const float* __restrict__ gcn_w,
    float* __restrict__ p1t,
    float* __restrict__ p2b,
    float* __restrict__ xwt)
{
    __shared__ float sred[8][32];
    const int t  = threadIdx.x;
    const int tc = t & 31;
    const int kc = t >> 5;
    const int cg = blockIdx.x;          // 0..4
    const int i  = blockIdx.y;          // 0..511

    const float* fp = features + (size_t)i * DD + kc * 64;

    float acc;
    if (cg < 2) {
        // W1a cols 0..63: cg*32+tc ; stride 64
        acc = dot64<HH>(fp, rel_w1 + cg * 32 + tc + (size_t)kc * 64 * HH);
    } else if (cg < 4) {
        // W1b cols 0..63
        acc = dot64<HH>(fp, rel_w1 + (size_t)DD * HH + (cg - 2) * 32 + tc
                            + (size_t)kc * 64 * HH);
    } else {
        acc = dot64<OUTC>(fp, gcn_w + tc + (size_t)kc * 64 * OUTC);
    }

    sred[kc][tc] = acc;
    __syncthreads();

    if (t < 32) {
        float s = sred[0][t] + sred[1][t] + sred[2][t] + sred[3][t]
                + sred[4][t] + sred[5][t] + sred[6][t] + sred[7][t];
        if (cg < 2) {
            int c = cg * 32 + t;
            p1t[(size_t)c * NN + i] = s;
        } else if (cg < 4) {
            int h = (cg - 2) * 32 + t;
            p2b[(size_t)i * HH + h] = s + rel_b1[h];
        } else {
            xwt[(size_t)t * NN + i] = s;
        }
    }
}

// K2: araw[i][j] = sigmoid(relu(P1[j]+P2b[i]) . w2 + b2) + (i==j)
//     rdv[i] = 1/sqrt(rowsum + 1)
__global__ __launch_bounds__(256) void k2_adj(
    const float* __restrict__ p1t,
    const float* __restrict__ p2b,
    const float* __restrict__ rel_w2,
    const float* __restrict__ rel_b2,
    float* __restrict__ araw,     // d_out A region (raw, normalized later)
    float* __restrict__ rdv)
{
    const int TI = 2;
    __shared__ float sp2[TI][HH];
    __shared__ float sw2[HH];
    __shared__ float sred[TI][4];
    const int t  = threadIdx.x;
    const int i0 = blockIdx.x * TI;

    if (t < HH) sw2[t] = rel_w2[t];
    else if (t < HH + TI * HH) {
        int q = t - HH;                      // 0..127 -> rows i0, i0+1
        sp2[q >> 6][q & 63] = p2b[(size_t)i0 * HH + q];
    }
    __syncthreads();

    const float b2 = rel_b2[0];
    float rs0 = 0.f, rs1 = 0.f;

    #pragma unroll
    for (int jj = 0; jj < 2; ++jj) {
        int j = t + jj * 256;
        float a0 = b2, a1 = b2;
        #pragma unroll 8
        for (int k = 0; k < HH; ++k) {
            float pv = p1t[(size_t)k * NN + j];   // coalesced across lanes
            float w  = sw2[k];                    // LDS broadcast
            a0 = fmaf(fmaxf(pv + sp2[0][k], 0.f), w, a0);
            a1 = fmaf(fmaxf(pv + sp2[1][k], 0.f), w, a1);
        }
        a0 = 1.f / (1.f + expf(-a0)); if (j == i0)     a0 += 1.f;
        a1 = 1.f / (1.f + expf(-a1)); if (j == i0 + 1) a1 += 1.f;
        araw[(size_t)(i0 + 0) * NN + j] = a0;
        araw[(size_t)(i0 + 1) * NN + j] = a1;
        rs0 += a0; rs1 += a1;
    }

    // 64-lane shuffle reduce, then cross-wave via LDS
    #pragma unroll
    for (int off = 32; off > 0; off >>= 1) {
        rs0 += __shfl_down(rs0, off, 64);
        rs1 += __shfl_down(rs1, off, 64);
    }
    int wave = t >> 6, lane = t & 63;
    if (lane == 0) { sred[0][wave] = rs0; sred[1][wave] = rs1; }
    __syncthreads();
    if (t < TI) {
        float s = sred[t][0] + sred[t][1] + sred[t][2] + sred[t][3];
        rdv[i0 + t] = 1.0f / sqrtf(s + 1.0f);
    }
}

// K3: normalize A in place; x = relu(gamma*(A@XW + b)*inv_sqrt(1+eps) + beta)
__global__ __launch_bounds__(256) void k3_gcn(
    const float* __restrict__ xwt,
    const float* __restrict__ rdv,
    const float* __restrict__ gcn_b,
    const float* __restrict__ bn_gamma,
    const float* __restrict__ bn_beta,
    float* __restrict__ outx,
    float* __restrict__ outA)
{
    __shared__ float sdv[NN];                 // 2 KB
    __shared__ float sred[4][OUTC];
    const int t = threadIdx.x;
    const int i = blockIdx.x;

    sdv[t] = rdv[t];
    sdv[t + 256] = rdv[t + 256];
    __syncthreads();

    const float ri = sdv[i];
    const int j0 = t, j1 = t + 256;
    float a0 = outA[(size_t)i * NN + j0] * (ri * sdv[j0]);
    float a1 = outA[(size_t)i * NN + j1] * (ri * sdv[j1]);
    outA[(size_t)i * NN + j0] = a0;
    outA[(size_t)i * NN + j1] = a1;

    float acc[OUTC];
    #pragma unroll
    for (int o = 0; o < OUTC; ++o) {
        acc[o] = fmaf(a0, xwt[(size_t)o * NN + j0],
                      a1 * xwt[(size_t)o * NN + j1]);   // coalesced loads
    }

    #pragma unroll
    for (int o = 0; o < OUTC; ++o)
        #pragma unroll
        for (int off = 32; off > 0; off >>= 1)
            acc[o] += __shfl_down(acc[o], off, 64);

    int wave = t >> 6, lane = t & 63;
    if (lane == 0) {
        #pragma unroll
        for (int o = 0; o < OUTC; ++o) sred[wave][o] = acc[o];
    }
    __syncthreads();
    if (t < OUTC) {
        float v = sred[0][t] + sred[1][t] + sred[2][t] + sred[3][t] + gcn_b[t];
        float invs = 1.0f / sqrtf(1.0f + 1e-5f);
        v = bn_gamma[t] * v * invs + bn_beta[t];
        outx[(size_t)i * OUTC + t] = fmaxf(v, 0.f);
    }
}

extern "C" void kernel_launch(void* const* d_in, const int* in_sizes, int n_in,
                              void* d_out, int out_size, void* d_ws, size_t ws_size,
                              hipStream_t stream) {
    const float* features = (const float*)d_in[0];
    const float* rel_w1   = (const float*)d_in[1];
    const float* rel_b1   = (const float*)d_in[2];
    const float* rel_w2   = (const float*)d_in[3];
    const float* rel_b2   = (const float*)d_in[4];
    const float* gcn_w    = (const float*)d_in[5];
    const float* gcn_b    = (const float*)d_in[6];
    const float* bn_gamma = (const float*)d_in[7];
    const float* bn_beta  = (const float*)d_in[8];

    float* out  = (float*)d_out;
    float* outx = out;                 // (512, 32)
    float* outA = out + NN * OUTC;     // (512, 512)

    float* ws  = (float*)d_ws;
    float* p1t = ws;                   // [64][512]
    float* p2b = ws + 32768;           // [512][64]
    float* xwt = ws + 65536;           // [32][512]
    float* rdv = ws + 81920;           // [512]

    hipLaunchKernelGGL(k1_gemm, dim3(5, 512), dim3(256), 0, stream,
                       features, rel_w1, rel_b1, gcn_w, p1t, p2b, xwt);
    hipLaunchKernelGGL(k2_adj, dim3(256), dim3(256), 0, stream,
                       p1t, p2b, rel_w2, rel_b2, outA, rdv);
    hipLaunchKernelGGL(k3_gcn, dim3(512), dim3(256), 0, stream,
                       xwt, rdv, gcn_b, bn_gamma, bn_beta, outx, outA);
}